// Round 1
// baseline (251.181 us; speedup 1.0000x reference)
//
#include <hip/hip_runtime.h>
#include <math.h>

// Math reduction (EPS=1e-12 negligible for x ~ N(0,1)):
//   gain_j = logit x_j exactly; base = sum_j softplus(x_j);
//   pos = sum_{m=1, x>0} x ; best = max_{m=1} x
//   per_sample = base - (pos>0 ? pos : best);  answer = mean over rows.
//
// Round-7: persistent wave-per-row + 2-row software pipeline + nt loads.
// Evidence: with nt loads the row kernel dropped below the 76us harness fills
// (absent from top-5) -> nt dodged the suspected L1 miss-queue wall (~2.8 TB/s
// = 32 lines x 128B / 375ns per CU). Remaining gap to the ~42us read floor is
// MLP duty cycle: old structure had 2 loads/thread then a dead tail (compute +
// 18-shfl reduce + barrier + block retire) with nothing in flight. New
// structure: each wave owns 8 consecutive rows, prefetches row k+1's 8x float4
// nt loads before computing row k. No __syncthreads, 1024 blocks total, static
// double buffers (no runtime-indexed arrays -> no scratch).
// Finalize: unchanged deterministic 2-stage tree (no atomics).

constexpr int B = 32768;
constexpr int C = 1000;
constexpr int C4 = C / 4;                 // 250 float4 per row
constexpr int THREADS = 256;
constexpr int WAVES_PER_BLOCK = THREADS / 64;        // 4
constexpr int ROWS_PER_WAVE = 8;
constexpr int NBLOCKS = B / (WAVES_PER_BLOCK * ROWS_PER_WAVE);  // 1024

typedef float f32x4 __attribute__((ext_vector_type(4)));

__device__ __forceinline__ void elem_update(float x, float m,
                                            float& base, float& pos, float& best) {
    // softplus(x) = max(x,0) + log(1 + exp(-|x|))
    float e  = __expf(-fabsf(x));
    float xp = fmaxf(x, 0.0f);
    base += xp + __logf(1.0f + e);
    pos  += m * xp;                       // m in {0,1}; only x>0 contributes
    if (m != 0.0f) best = fmaxf(best, x);
}

// Issue all 8 nt float4 loads for one row (lanes cover 4 chunks of 64 float4;
// chunk 3 is partial: idx 192..249 -> lanes 0..57 active).
__device__ __forceinline__ void load_row(const float* __restrict__ Xrow,
                                         const float* __restrict__ Mrow,
                                         int lane,
                                         f32x4 (&xb)[4], f32x4 (&mb)[4]) {
    const f32x4* x4 = reinterpret_cast<const f32x4*>(Xrow);
    const f32x4* m4 = reinterpret_cast<const f32x4*>(Mrow);
    #pragma unroll
    for (int j = 0; j < 4; ++j) {
        const int idx = j * 64 + lane;
        if (idx < C4) {
            xb[j] = __builtin_nontemporal_load(x4 + idx);
            mb[j] = __builtin_nontemporal_load(m4 + idx);
        }
    }
}

// Consume one row's buffers; returns per-row loss in lane 0.
__device__ __forceinline__ float row_result(int lane,
                                            const f32x4 (&xb)[4],
                                            const f32x4 (&mb)[4]) {
    float base = 0.f, pos = 0.f, best = -INFINITY;
    #pragma unroll
    for (int j = 0; j < 4; ++j) {
        const int idx = j * 64 + lane;
        if (idx < C4) {
            elem_update(xb[j].x, mb[j].x, base, pos, best);
            elem_update(xb[j].y, mb[j].y, base, pos, best);
            elem_update(xb[j].z, mb[j].z, base, pos, best);
            elem_update(xb[j].w, mb[j].w, base, pos, best);
        }
    }
    // wave-level reduction (64 lanes), no barrier needed
    #pragma unroll
    for (int off = 32; off > 0; off >>= 1) {
        base += __shfl_down(base, off, 64);
        pos  += __shfl_down(pos,  off, 64);
        best  = fmaxf(best, __shfl_down(best, off, 64));
    }
    return base - ((pos > 0.f) ? pos : best);
}

__global__ __launch_bounds__(THREADS)
void row_loss_kernel(const float* __restrict__ X,
                     const float* __restrict__ M,
                     float* __restrict__ partial) {
    const int wid  = blockIdx.x * WAVES_PER_BLOCK + (threadIdx.x >> 6);
    const int lane = threadIdx.x & 63;
    const int row0 = wid * ROWS_PER_WAVE;

    // Two named buffer sets -> all register indices compile-time constant.
    f32x4 xa[4], ma[4], xc[4], mc[4];

    load_row(X + (size_t)row0 * C, M + (size_t)row0 * C, lane, xa, ma);

    #pragma unroll
    for (int k = 0; k < ROWS_PER_WAVE; ++k) {
        const int r = row0 + k;
        // prefetch next row into the buffer NOT being consumed this iteration
        if (k + 1 < ROWS_PER_WAVE) {
            const float* Xn = X + (size_t)(r + 1) * C;
            const float* Mn = M + (size_t)(r + 1) * C;
            if (k & 1) load_row(Xn, Mn, lane, xa, ma);
            else       load_row(Xn, Mn, lane, xc, mc);
        }
        const float res = (k & 1) ? row_result(lane, xc, mc)
                                  : row_result(lane, xa, ma);
        if (lane == 0) partial[r] = res;
    }
}

// Stage 1: 64 blocks x 256 threads; block b reduces partial[512b .. 512b+511]
__global__ __launch_bounds__(256)
void finalize1_kernel(const float* __restrict__ partial, float* __restrict__ mid) {
    const int b = blockIdx.x;
    const int t = threadIdx.x;
    float v = partial[b * 512 + t] + partial[b * 512 + t + 256];

    #pragma unroll
    for (int off = 32; off > 0; off >>= 1)
        v += __shfl_down(v, off, 64);

    __shared__ float s[4];
    const int w    = t >> 6;
    const int lane = t & 63;
    if (lane == 0) s[w] = v;
    __syncthreads();
    if (t == 0) mid[b] = (s[0] + s[1]) + (s[2] + s[3]);
}

// Stage 2: 1 block x 64 threads; double-precision sum of 64 values, mean.
__global__ __launch_bounds__(64)
void finalize2_kernel(const float* __restrict__ mid, float* __restrict__ out) {
    double v = (double)mid[threadIdx.x];
    #pragma unroll
    for (int off = 32; off > 0; off >>= 1)
        v += __shfl_down(v, off, 64);
    if (threadIdx.x == 0) out[0] = (float)(v / (double)B);
}

extern "C" void kernel_launch(void* const* d_in, const int* in_sizes, int n_in,
                              void* d_out, int out_size, void* d_ws, size_t ws_size,
                              hipStream_t stream) {
    const float* X  = (const float*)d_in[0];
    const float* M  = (const float*)d_in[1];
    float* out      = (float*)d_out;
    float* partial  = (float*)d_ws;          // 32768 floats
    float* mid      = partial + B;           // 64 floats

    row_loss_kernel<<<NBLOCKS, THREADS, 0, stream>>>(X, M, partial);
    finalize1_kernel<<<64, 256, 0, stream>>>(partial, mid);
    finalize2_kernel<<<1, 64, 0, stream>>>(mid, out);
}